// Round 3
// baseline (288.475 us; speedup 1.0000x reference)
//
#include <hip/hip_runtime.h>
#include <math.h>

// B=32, L=512, CIN=32, D=128, N=64, E=3, PL=16, ST=8, PRED=96, P=64, BC=1024
// Fused: RevIN + embed + 3x(LN->conv->GELU->GLU MFMA->residual) all with h in LDS.
// h final stored bf16 (BC, 8192=d*64+p) for the head GEMM.

typedef __attribute__((ext_vector_type(8))) short bf16x8;
typedef __attribute__((ext_vector_type(4))) float f32x4;

__device__ __forceinline__ ushort f2bf(float f) {
  uint u = __float_as_uint(f);
  return (ushort)((u + 0x7FFFu + ((u >> 16) & 1u)) >> 16);
}

// z-tile swizzle (LN write / conv read), 2-way max
#define ZIDX(p, d) ((p) * 128 + ((d) ^ (((p) & 7) << 2)))
// h-tile swizzle: bit4 of p XORed with (d^(d>>2))&1 -> LN reads (d bit0 varies per lane)
// and epilogue RMW (d bit2 varies per lane) both spread across 32 banks. float4-safe.
#define HIDX(d, p) ((d) * 64 + ((p) ^ (((((d) >> 2) ^ (d)) & 1) << 4)))

// ---------------- S4D kernel K[e][p][h] ----------------
__global__ __launch_bounds__(64) void kcomp_kernel(const float* __restrict__ log_dt,
                                                   const float* __restrict__ arl,
                                                   const float* __restrict__ aimg,
                                                   const float* __restrict__ cre,
                                                   const float* __restrict__ cim,
                                                   float* __restrict__ K_all_t) {
  int bid = blockIdx.x;
  int e = bid >> 7, hh = bid & 127;
  int lane = threadIdx.x;
  __shared__ float cr[64], ci[64], dr[64], di[64];
  float dt = expf(log_dt[e * 128 + hh]);
  {
    int n = lane;
    size_t base = ((size_t)e * 128 + hh) * 64 + n;
    float are = -expf(arl[base]);
    float aim = aimg[base];
    float dre = are * dt, dim = aim * dt;
    float ex = expf(dre);
    float cs = cosf(dim), sn = sinf(dim);
    float er = ex * cs - 1.f, ei = ex * sn;
    float invd = 1.f / (are * are + aim * aim);
    float qr = (er * are + ei * aim) * invd;
    float qi = (ei * are - er * aim) * invd;
    float tr = cre[base], ti = cim[base];
    cr[n] = tr * qr - ti * qi;
    ci[n] = tr * qi + ti * qr;
    dr[n] = dre; di[n] = dim;
  }
  __syncthreads();
  int p = lane;
  float fp = (float)p;
  float sum = 0.f;
#pragma unroll 4
  for (int n = 0; n < 64; ++n) {
    float er = expf(dr[n] * fp);
    float ang = di[n] * fp;
    sum += er * (cr[n] * cosf(ang) - ci[n] * sinf(ang));
  }
  K_all_t[(size_t)e * 8192 + p * 128 + hh] = 2.f * sum;
}

// ---------------- Prep: bf16 W_out^T, bf16 W_head^T, PE table [d][p] ----------------
__global__ __launch_bounds__(256) void prep_kernel(const float* __restrict__ W_out,
                                                   const float* __restrict__ W_head,
                                                   ushort* __restrict__ wt,
                                                   ushort* __restrict__ wth,
                                                   float* __restrict__ pet) {
  __shared__ ushort lbuf[12800];
  int bid = blockIdx.x, tid = threadIdx.x;
  if (bid < 64) {                 // W_head^T tile: wth[t][f] (96 x 8192)
    int f0 = bid << 7;
    for (int i = tid; i < 12288; i += 256) {
      int f = i / 96, t = i - f * 96;
      lbuf[f * 100 + t] = f2bf(W_head[(size_t)(f0 + f) * 96 + t]);
    }
    __syncthreads();
    for (int i = tid; i < 12288; i += 256) {
      int t = i >> 7, f = i & 127;
      wth[(size_t)t * 8192 + f0 + f] = lbuf[f * 100 + t];
    }
  } else if (bid < 67) {          // W_out^T per e: wt[e][g][h] (256 x 128)
    int e = bid - 64;
    for (int h0 = 0; h0 < 128; h0 += 32) {
      __syncthreads();
      for (int i = tid; i < 8192; i += 256) {
        int hh = i >> 8, g = i & 255;
        lbuf[hh * 260 + g] = f2bf(W_out[e * 32768 + (h0 + hh) * 256 + g]);
      }
      __syncthreads();
      for (int i = tid; i < 8192; i += 256) {
        int g = i >> 5, hh = i & 31;
        wt[(size_t)(e * 256 + g) * 128 + h0 + hh] = lbuf[hh * 260 + g];
      }
    }
  } else {                        // PE table transposed: pet[d*64+p]
    int i = (bid - 67) * 256 + tid;
    int d = i >> 6, p = i & 63;
    float freq = expf((float)(d & ~1) * (-0.0719557841f));  // -ln(10000)/128
    float ang = (float)p * freq;
    pet[i] = (d & 1) ? cosf(ang) : sinf(ang);
  }
}

// ---------------- Fused: RevIN + embed + 3 layers, h resident in LDS ----------------
__global__ __launch_bounds__(256, 2) void fused_kernel(const float* __restrict__ x,
                                                       const float* __restrict__ W_embed,
                                                       const float* __restrict__ pet,
                                                       const float* __restrict__ K_all_t,
                                                       const float* __restrict__ ln_g,
                                                       const float* __restrict__ ln_b,
                                                       const float* __restrict__ D_skip,
                                                       const ushort* __restrict__ wt,
                                                       const float* __restrict__ b_out,
                                                       ushort* __restrict__ hb,
                                                       float* __restrict__ meanw,
                                                       float* __restrict__ stdw) {
  __shared__ float hsm[8192];     // h residual stream, HIDX-swizzled [128 d][64 p]
  __shared__ float zl[8192];      // z (ZIDX-swizzled); also xts/Wel in embed, ys (bf16) in MFMA
  int bc = blockIdx.x, tid = threadIdx.x;
  int b = bc >> 5, c = bc & 31;
  int w = tid >> 6, l = tid & 63;

  // ---- RevIN: mean/std over L=512 for this (b,c) ----
  const float* xb = x + (size_t)b * 512 * 32 + c;
  float v0 = xb[(size_t)tid * 32];
  float v1 = xb[(size_t)(tid + 256) * 32];
  float s = v0 + v1, sq = v0 * v0 + v1 * v1;
#pragma unroll
  for (int off = 1; off < 64; off <<= 1) {
    s += __shfl_xor(s, off);
    sq += __shfl_xor(sq, off);
  }
  if (l == 0) { hsm[w] = s; hsm[4 + w] = sq; }
  __syncthreads();
  s = hsm[0] + hsm[1] + hsm[2] + hsm[3];
  sq = hsm[4] + hsm[5] + hsm[6] + hsm[7];
  float mu = s * (1.f / 512.f);
  float var = sq * (1.f / 512.f) - mu * mu;
  float sd = sqrtf(var + 1e-5f);
  float inv = 1.f / sd;
  if (tid == 0) { meanw[bc] = mu; stdw[bc] = sd; }
  float* xts = zl;          // [528]
  float* Wel = zl + 1024;   // [2048]
  xts[tid] = (v0 - mu) * inv;
  xts[tid + 256] = (v1 - mu) * inv;
  if (tid == 255) {
    float ev = (v1 - mu) * inv;
#pragma unroll
    for (int i = 0; i < 16; ++i) xts[512 + i] = ev;
  }
  for (int i = tid; i < 2048; i += 256) Wel[i] = W_embed[i];
  __syncthreads();

  // ---- Patch embed into hsm ----
  {
    int p = tid & 63, dg = tid >> 6;
    float xr[16];
    const float4* xf = (const float4*)xts;
#pragma unroll
    for (int i = 0; i < 4; ++i) {
      float4 a = xf[p * 2 + i];
      xr[4 * i] = a.x; xr[4 * i + 1] = a.y; xr[4 * i + 2] = a.z; xr[4 * i + 3] = a.w;
    }
#pragma unroll 4
    for (int dd = 0; dd < 32; ++dd) {
      int d = dg * 32 + dd;
      float acc = 0.f;
#pragma unroll
      for (int k = 0; k < 16; ++k) acc += xr[k] * Wel[k * 128 + d];
      hsm[HIDX(d, p)] = acc + pet[d * 64 + p];
    }
  }

  int hh = tid & 127, pg = tid >> 7;
  int lr = l & 15, lk = l >> 4;

  for (int e = 0; e < 3; ++e) {
    __syncthreads();
    // ---- LayerNorm over D at each p (4 threads per p) ----
    {
      int p = tid >> 2, sub = tid & 3;
      float hv[32];
      float ls = 0.f, lq = 0.f;
#pragma unroll
      for (int j = 0; j < 32; ++j) {
        int d = sub + 4 * j;
        float vv = hsm[HIDX(d, p)];
        hv[j] = vv; ls += vv; lq += vv * vv;
      }
      ls += __shfl_xor(ls, 1); ls += __shfl_xor(ls, 2);
      lq += __shfl_xor(lq, 1); lq += __shfl_xor(lq, 2);
      float lmu = ls * (1.f / 128.f);
      float lvar = lq * (1.f / 128.f) - lmu * lmu;
      float istd = rsqrtf(lvar + 1e-5f);
#pragma unroll
      for (int j = 0; j < 32; ++j) {
        int d = sub + 4 * j;
        zl[ZIDX(p, d)] = (hv[j] - lmu) * istd * ln_g[e * 128 + d] + ln_b[e * 128 + d];
      }
    }
    // K into registers (L2-resident, coalesced per wave)
    float kr[64];
    {
      const float* kb = K_all_t + e * 8192 + hh;
#pragma unroll
      for (int i = 0; i < 64; ++i) kr[i] = kb[i * 128];
    }
    __syncthreads();

    // ---- causal conv, interleaved p-split (thread owns p = 2j+pg) ----
    float y[32];
#pragma unroll
    for (int j = 0; j < 32; ++j) y[j] = 0.f;
    if (pg == 0) {
#pragma unroll
      for (int q = 0; q < 63; ++q) {
        float zv = zl[ZIDX(q, hh)];
#pragma unroll
        for (int j = (q + 1) >> 1; j < 32; ++j) y[j] += zv * kr[2 * j - q];
      }
    } else {
#pragma unroll
      for (int q = 0; q < 64; ++q) {
        float zv = zl[ZIDX(q, hh)];
#pragma unroll
        for (int j = q >> 1; j < 32; ++j) y[j] += zv * kr[2 * j + 1 - q];
      }
    }
    // skip + exact GELU
    {
      float dsk = D_skip[e * 128 + hh];
#pragma unroll
      for (int j = 0; j < 32; ++j) {
        int p = 2 * j + pg;
        float u = zl[ZIDX(p, hh)];
        float t = y[j] + u * dsk;
        y[j] = 0.5f * t * (1.f + erff(t * 0.70710678f));
      }
    }
    __syncthreads();                 // all zl reads done; ys aliases zl
    ushort* ys = (ushort*)zl;        // [64 p][128 h] bf16, 16B-slot XOR swizzle
    {
      int slot = hh >> 3;
#pragma unroll
      for (int j = 0; j < 32; ++j) {
        int p = 2 * j + pg;
        ys[p * 128 + ((slot ^ (p & 15)) << 3) + (hh & 7)] = f2bf(y[j]);
      }
    }
    __syncthreads();

    // ---- MFMA GLU linear: v[g][p] = sum_h Wt[g][h] * y^T[p][h] ----
    f32x4 acc[4][4];
#pragma unroll
    for (int m = 0; m < 4; ++m)
#pragma unroll
      for (int n = 0; n < 4; ++n) acc[m][n] = (f32x4){0.f, 0.f, 0.f, 0.f};
    const ushort* wbase = wt + (size_t)e * 32768;
#pragma unroll
    for (int ks = 0; ks < 4; ++ks) {
      int kofs = ks * 32 + lk * 8;
      bf16x8 a[4], bfr[4];
#pragma unroll
      for (int mf = 0; mf < 4; ++mf) {
        int gm = (mf < 2) ? (w * 32 + mf * 16) : (128 + w * 32 + (mf - 2) * 16);
        a[mf] = *(const bf16x8*)(wbase + (size_t)(gm + lr) * 128 + kofs);
      }
#pragma unroll
      for (int nf = 0; nf < 4; ++nf) {
        int p = nf * 16 + lr;
        int slot = (ks * 4 + lk) ^ (p & 15);
        bfr[nf] = *(const bf16x8*)(ys + p * 128 + slot * 8);
      }
#pragma unroll
      for (int mf = 0; mf < 4; ++mf)
#pragma unroll
        for (int nf = 0; nf < 4; ++nf)
          acc[mf][nf] = __builtin_amdgcn_mfma_f32_16x16x32_bf16(a[mf], bfr[nf], acc[mf][nf], 0, 0, 0);
    }

    // ---- epilogue: bias + GLU + residual into hsm ----
#pragma unroll
    for (int mf = 0; mf < 2; ++mf)
#pragma unroll
      for (int nf = 0; nf < 4; ++nf)
#pragma unroll
        for (int r = 0; r < 4; ++r) {
          int g = w * 32 + mf * 16 + lk * 4 + r;
          int p = nf * 16 + lr;
          float vv1 = acc[mf][nf][r] + b_out[e * 256 + g];
          float vv2 = acc[mf + 2][nf][r] + b_out[e * 256 + 128 + g];
          float sig = 1.f / (1.f + expf(-vv2));
          int idx = HIDX(g, p);
          hsm[idx] = hsm[idx] + vv1 * sig;
        }
  }
  __syncthreads();

  // ---- store h as bf16, coalesced ushort4 ----
  ushort* hrow = hb + (size_t)bc * 8192;
#pragma unroll
  for (int j = 0; j < 8; ++j) {
    int f = j * 1024 + tid * 4;
    int d = f >> 6, p0 = f & 63;
    float4 hv4 = *(const float4*)(hsm + HIDX(d, p0));
    ushort4 o;
    o.x = f2bf(hv4.x); o.y = f2bf(hv4.y); o.z = f2bf(hv4.z); o.w = f2bf(hv4.w);
    *(ushort4*)(hrow + f) = o;
  }
}

// ---------------- Head: bf16 GEMM (1024 x 96 x 8192), grid (b, kc) = 32x8 ----------------
__global__ __launch_bounds__(256) void head_kernel(const ushort* __restrict__ hb,
                                                   const ushort* __restrict__ wth,
                                                   float* __restrict__ part) {
  __shared__ float sred[12288];   // [4 waves][32 c][96 t]
  int bid = blockIdx.x;
  int b = bid >> 3, kc = bid & 7;
  int tid = threadIdx.x, w = tid >> 6, l = tid & 63;
  int lr = l & 15, lk = l >> 4;
  int kwbase = kc * 1024 + w * 256;
  f32x4 acc[2][6];
#pragma unroll
  for (int m = 0; m < 2; ++m)
#pragma unroll
    for (int n = 0; n < 6; ++n) acc[m][n] = (f32x4){0.f, 0.f, 0.f, 0.f};
#pragma unroll 2
  for (int ks = 0; ks < 8; ++ks) {
    int kb = kwbase + ks * 32 + lk * 8;
    bf16x8 a[2];
#pragma unroll
    for (int mf = 0; mf < 2; ++mf)
      a[mf] = *(const bf16x8*)(hb + (size_t)(b * 32 + mf * 16 + lr) * 8192 + kb);
#pragma unroll
    for (int nf = 0; nf < 6; ++nf) {
      bf16x8 bb = *(const bf16x8*)(wth + (size_t)(nf * 16 + lr) * 8192 + kb);
#pragma unroll
      for (int mf = 0; mf < 2; ++mf)
        acc[mf][nf] = __builtin_amdgcn_mfma_f32_16x16x32_bf16(a[mf], bb, acc[mf][nf], 0, 0, 0);
    }
  }
#pragma unroll
  for (int mf = 0; mf < 2; ++mf)
#pragma unroll
    for (int nf = 0; nf < 6; ++nf)
#pragma unroll
      for (int r = 0; r < 4; ++r) {
        int cc = mf * 16 + lk * 4 + r;
        int t = nf * 16 + lr;
        sred[w * 3072 + cc * 96 + t] = acc[mf][nf][r];
      }
  __syncthreads();
  for (int i = tid; i < 3072; i += 256) {
    float s = sred[i] + sred[3072 + i] + sred[6144 + i] + sred[9216 + i];
    part[(size_t)(kc * 32 + b) * 3072 + i] = s;
  }
}

// ---------------- Reduce partials + bias + denorm ----------------
__global__ __launch_bounds__(256) void reduce_kernel(const float* __restrict__ part,
                                                     const float* __restrict__ b_head,
                                                     const float* __restrict__ meanw,
                                                     const float* __restrict__ stdw,
                                                     float* __restrict__ out) {
  int o = blockIdx.x * 256 + threadIdx.x;
  int c = o & 31;
  int bt = o >> 5;
  int t = bt % 96;
  int b = bt / 96;
  float s = b_head[t];
#pragma unroll
  for (int fs = 0; fs < 8; ++fs)
    s += part[(((size_t)fs * 32 + b) * 32 + c) * 96 + t];
  out[o] = s * stdw[b * 32 + c] + meanw[b * 32 + c];
}

extern "C" void kernel_launch(void* const* d_in, const int* in_sizes, int n_in,
                              void* d_out, int out_size, void* d_ws, size_t ws_size,
                              hipStream_t stream) {
  const float* x_enc   = (const float*)d_in[0];
  const float* W_embed = (const float*)d_in[4];
  const float* ln_g    = (const float*)d_in[5];
  const float* ln_b    = (const float*)d_in[6];
  const float* log_dt  = (const float*)d_in[7];
  const float* arl     = (const float*)d_in[8];
  const float* aimg    = (const float*)d_in[9];
  const float* cre     = (const float*)d_in[10];
  const float* cim     = (const float*)d_in[11];
  const float* dskip   = (const float*)d_in[12];
  const float* wout    = (const float*)d_in[13];
  const float* bout    = (const float*)d_in[14];
  const float* whead   = (const float*)d_in[15];
  const float* bhead   = (const float*)d_in[16];

  float* ws    = (float*)d_ws;
  float* meanw = ws;                        // 1024
  float* stdw  = meanw + 1024;              // 1024
  float* kall  = stdw + 1024;               // 24576
  ushort* wt   = (ushort*)(kall + 24576);   // 98304 ushorts = 49152 floats
  ushort* wth  = (ushort*)(kall + 24576 + 49152);   // 786432 ushorts = 393216 floats
  float* pet   = kall + 24576 + 49152 + 393216;     // 8192
  ushort* hb   = (ushort*)(pet + 8192);     // 8388608 ushorts = 4194304 floats
  float* partw = pet + 8192 + 4194304;      // 786432

  float* out = (float*)d_out;

  prep_kernel<<<99, 256, 0, stream>>>(wout, whead, wt, wth, pet);
  kcomp_kernel<<<384, 64, 0, stream>>>(log_dt, arl, aimg, cre, cim, kall);
  fused_kernel<<<1024, 256, 0, stream>>>(x_enc, W_embed, pet, kall, ln_g, ln_b,
                                         dskip, wt, bout, hb, meanw, stdw);
  head_kernel<<<256, 256, 0, stream>>>(hb, wth, partw);
  reduce_kernel<<<384, 256, 0, stream>>>(partw, bhead, meanw, stdw, out);
}

// Round 4
// 253.673 us; speedup vs baseline: 1.1372x; 1.1372x over previous
//
#include <hip/hip_runtime.h>
#include <math.h>

// B=32, L=512, CIN=32, D=128, N=64, E=3, PL=16, ST=8, PRED=96, P=64, BC=1024
// Fused: RevIN + embed + 3x(LN->conv->GELU->GLU MFMA->residual) with h in LDS.
// e-loop kept UNROLLED ONCE (unroll 1): full unroll tripled code size past I$ and
// forced scratch spills at the 128-VGPR cap (R3: +72MB fetch AND +72MB write).

typedef __attribute__((ext_vector_type(8))) short bf16x8;
typedef __attribute__((ext_vector_type(4))) float f32x4;

__device__ __forceinline__ ushort f2bf(float f) {
  uint u = __float_as_uint(f);
  return (ushort)((u + 0x7FFFu + ((u >> 16) & 1u)) >> 16);
}

// z-tile swizzle (LN write / conv read), 2-way max
#define ZIDX(p, d) ((p) * 128 + ((d) ^ (((p) & 7) << 2)))
// h-tile swizzle: bit4 of p XORed with (d^(d>>2))&1
#define HIDX(d, p) ((d) * 64 + ((p) ^ (((((d) >> 2) ^ (d)) & 1) << 4)))

// ---------------- S4D kernel K[e][p][h] ----------------
__global__ __launch_bounds__(64) void kcomp_kernel(const float* __restrict__ log_dt,
                                                   const float* __restrict__ arl,
                                                   const float* __restrict__ aimg,
                                                   const float* __restrict__ cre,
                                                   const float* __restrict__ cim,
                                                   float* __restrict__ K_all_t) {
  int bid = blockIdx.x;
  int e = bid >> 7, hh = bid & 127;
  int lane = threadIdx.x;
  __shared__ float cr[64], ci[64], dr[64], di[64];
  float dt = expf(log_dt[e * 128 + hh]);
  {
    int n = lane;
    size_t base = ((size_t)e * 128 + hh) * 64 + n;
    float are = -expf(arl[base]);
    float aim = aimg[base];
    float dre = are * dt, dim = aim * dt;
    float ex = expf(dre);
    float cs = cosf(dim), sn = sinf(dim);
    float er = ex * cs - 1.f, ei = ex * sn;
    float invd = 1.f / (are * are + aim * aim);
    float qr = (er * are + ei * aim) * invd;
    float qi = (ei * are - er * aim) * invd;
    float tr = cre[base], ti = cim[base];
    cr[n] = tr * qr - ti * qi;
    ci[n] = tr * qi + ti * qr;
    dr[n] = dre; di[n] = dim;
  }
  __syncthreads();
  int p = lane;
  float fp = (float)p;
  float sum = 0.f;
#pragma unroll 4
  for (int n = 0; n < 64; ++n) {
    float er = expf(dr[n] * fp);
    float ang = di[n] * fp;
    sum += er * (cr[n] * cosf(ang) - ci[n] * sinf(ang));
  }
  K_all_t[(size_t)e * 8192 + p * 128 + hh] = 2.f * sum;
}

// ---------------- Prep: bf16 W_out^T, bf16 W_head^T, PE table [d][p] ----------------
__global__ __launch_bounds__(256) void prep_kernel(const float* __restrict__ W_out,
                                                   const float* __restrict__ W_head,
                                                   ushort* __restrict__ wt,
                                                   ushort* __restrict__ wth,
                                                   float* __restrict__ pet) {
  __shared__ ushort lbuf[12800];
  int bid = blockIdx.x, tid = threadIdx.x;
  if (bid < 64) {                 // W_head^T tile: wth[t][f] (96 x 8192)
    int f0 = bid << 7;
    for (int i = tid; i < 12288; i += 256) {
      int f = i / 96, t = i - f * 96;
      lbuf[f * 100 + t] = f2bf(W_head[(size_t)(f0 + f) * 96 + t]);
    }
    __syncthreads();
    for (int i = tid; i < 12288; i += 256) {
      int t = i >> 7, f = i & 127;
      wth[(size_t)t * 8192 + f0 + f] = lbuf[f * 100 + t];
    }
  } else if (bid < 67) {          // W_out^T per e: wt[e][g][h] (256 x 128)
    int e = bid - 64;
    for (int h0 = 0; h0 < 128; h0 += 32) {
      __syncthreads();
      for (int i = tid; i < 8192; i += 256) {
        int hh = i >> 8, g = i & 255;
        lbuf[hh * 260 + g] = f2bf(W_out[e * 32768 + (h0 + hh) * 256 + g]);
      }
      __syncthreads();
      for (int i = tid; i < 8192; i += 256) {
        int g = i >> 5, hh = i & 31;
        wt[(size_t)(e * 256 + g) * 128 + h0 + hh] = lbuf[hh * 260 + g];
      }
    }
  } else {                        // PE table transposed: pet[d*64+p]
    int i = (bid - 67) * 256 + tid;
    int d = i >> 6, p = i & 63;
    float freq = expf((float)(d & ~1) * (-0.0719557841f));  // -ln(10000)/128
    float ang = (float)p * freq;
    pet[i] = (d & 1) ? cosf(ang) : sinf(ang);
  }
}

// ---------------- Fused: RevIN + embed + 3 layers, h resident in LDS ----------------
__global__ __launch_bounds__(256, 2) void fused_kernel(const float* __restrict__ x,
                                                       const float* __restrict__ W_embed,
                                                       const float* __restrict__ pet,
                                                       const float* __restrict__ K_all_t,
                                                       const float* __restrict__ ln_g,
                                                       const float* __restrict__ ln_b,
                                                       const float* __restrict__ D_skip,
                                                       const ushort* __restrict__ wt,
                                                       const float* __restrict__ b_out,
                                                       ushort* __restrict__ hb,
                                                       float* __restrict__ meanw,
                                                       float* __restrict__ stdw) {
  __shared__ float hsm[8192];     // h residual stream, HIDX-swizzled [128 d][64 p]  (32 KB)
  __shared__ float zl[8192];      // z (ZIDX-swizzled); xts/Wel during embed         (32 KB)
  __shared__ ushort ys[8192];     // y^T bf16 [64 p][128 h], 16B-slot XOR swizzle    (16 KB)
  int bc = blockIdx.x, tid = threadIdx.x;
  int b = bc >> 5, c = bc & 31;
  int w = tid >> 6, l = tid & 63;

  // ---- RevIN: mean/std over L=512 for this (b,c) ----
  const float* xb = x + (size_t)b * 512 * 32 + c;
  float v0 = xb[(size_t)tid * 32];
  float v1 = xb[(size_t)(tid + 256) * 32];
  float s = v0 + v1, sq = v0 * v0 + v1 * v1;
#pragma unroll
  for (int off = 1; off < 64; off <<= 1) {
    s += __shfl_xor(s, off);
    sq += __shfl_xor(sq, off);
  }
  if (l == 0) { hsm[w] = s; hsm[4 + w] = sq; }
  __syncthreads();
  s = hsm[0] + hsm[1] + hsm[2] + hsm[3];
  sq = hsm[4] + hsm[5] + hsm[6] + hsm[7];
  float mu = s * (1.f / 512.f);
  float var = sq * (1.f / 512.f) - mu * mu;
  float sd = sqrtf(var + 1e-5f);
  float inv = 1.f / sd;
  if (tid == 0) { meanw[bc] = mu; stdw[bc] = sd; }
  float* xts = zl;          // [528]
  float* Wel = zl + 1024;   // [2048]
  xts[tid] = (v0 - mu) * inv;
  xts[tid + 256] = (v1 - mu) * inv;
  if (tid == 255) {
    float ev = (v1 - mu) * inv;
#pragma unroll
    for (int i = 0; i < 16; ++i) xts[512 + i] = ev;
  }
  for (int i = tid; i < 2048; i += 256) Wel[i] = W_embed[i];
  __syncthreads();

  // ---- Patch embed into hsm ----
  {
    int p = tid & 63, dg = tid >> 6;
    float xr[16];
    const float4* xf = (const float4*)xts;
#pragma unroll
    for (int i = 0; i < 4; ++i) {
      float4 a = xf[p * 2 + i];
      xr[4 * i] = a.x; xr[4 * i + 1] = a.y; xr[4 * i + 2] = a.z; xr[4 * i + 3] = a.w;
    }
#pragma unroll 4
    for (int dd = 0; dd < 32; ++dd) {
      int d = dg * 32 + dd;
      float acc = 0.f;
#pragma unroll
      for (int k = 0; k < 16; ++k) acc += xr[k] * Wel[k * 128 + d];
      hsm[HIDX(d, p)] = acc + pet[d * 64 + p];
    }
  }

  int hh = tid & 127, pg = tid >> 7;
  int lr = l & 15, lk = l >> 4;

#pragma unroll 1
  for (int e = 0; e < 3; ++e) {
    __syncthreads();   // barrier A: prev epilogue hsm writes visible; zl free
    // ---- LayerNorm over D at each p (4 threads per p) ----
    {
      int p = tid >> 2, sub = tid & 3;
      float hv[32];
      float ls = 0.f, lq = 0.f;
#pragma unroll
      for (int j = 0; j < 32; ++j) {
        int d = sub + 4 * j;
        float vv = hsm[HIDX(d, p)];
        hv[j] = vv; ls += vv; lq += vv * vv;
      }
      ls += __shfl_xor(ls, 1); ls += __shfl_xor(ls, 2);
      lq += __shfl_xor(lq, 1); lq += __shfl_xor(lq, 2);
      float lmu = ls * (1.f / 128.f);
      float lvar = lq * (1.f / 128.f) - lmu * lmu;
      float istd = rsqrtf(lvar + 1e-5f);
#pragma unroll
      for (int j = 0; j < 32; ++j) {
        int d = sub + 4 * j;
        zl[ZIDX(p, d)] = (hv[j] - lmu) * istd * ln_g[e * 128 + d] + ln_b[e * 128 + d];
      }
    }
    // K into registers (L2-resident, coalesced per wave)
    float kr[64];
    {
      const float* kb = K_all_t + e * 8192 + hh;
#pragma unroll
      for (int i = 0; i < 64; ++i) kr[i] = kb[i * 128];
    }
    __syncthreads();   // barrier B: zl complete

    // ---- causal conv, interleaved p-split (thread owns p = 2j+pg) ----
    float y[32];
#pragma unroll
    for (int j = 0; j < 32; ++j) y[j] = 0.f;
    if (pg == 0) {
#pragma unroll
      for (int q = 0; q < 63; ++q) {
        float zv = zl[ZIDX(q, hh)];
#pragma unroll
        for (int j = (q + 1) >> 1; j < 32; ++j) y[j] += zv * kr[2 * j - q];
      }
    } else {
#pragma unroll
      for (int q = 0; q < 64; ++q) {
        float zv = zl[ZIDX(q, hh)];
#pragma unroll
        for (int j = q >> 1; j < 32; ++j) y[j] += zv * kr[2 * j + 1 - q];
      }
    }
    // skip + exact GELU -> ys (separate buffer: prev MFMA reads of ys are 2 barriers back)
    {
      float dsk = D_skip[e * 128 + hh];
      int slot = hh >> 3;
#pragma unroll
      for (int j = 0; j < 32; ++j) {
        int p = 2 * j + pg;
        float u = zl[ZIDX(p, hh)];
        float t = y[j] + u * dsk;
        float g = 0.5f * t * (1.f + erff(t * 0.70710678f));
        ys[p * 128 + ((slot ^ (p & 15)) << 3) + (hh & 7)] = f2bf(g);
      }
    }
    __syncthreads();   // barrier C: ys complete

    // ---- MFMA GLU linear: v[g][p] = sum_h Wt[g][h] * y^T[p][h] ----
    f32x4 acc[4][4];
#pragma unroll
    for (int m = 0; m < 4; ++m)
#pragma unroll
      for (int n = 0; n < 4; ++n) acc[m][n] = (f32x4){0.f, 0.f, 0.f, 0.f};
    const ushort* wbase = wt + (size_t)e * 32768;
#pragma unroll
    for (int ks = 0; ks < 4; ++ks) {
      int kofs = ks * 32 + lk * 8;
      bf16x8 a[4], bfr[4];
#pragma unroll
      for (int mf = 0; mf < 4; ++mf) {
        int gm = (mf < 2) ? (w * 32 + mf * 16) : (128 + w * 32 + (mf - 2) * 16);
        a[mf] = *(const bf16x8*)(wbase + (size_t)(gm + lr) * 128 + kofs);
      }
#pragma unroll
      for (int nf = 0; nf < 4; ++nf) {
        int p = nf * 16 + lr;
        int slot = (ks * 4 + lk) ^ (p & 15);
        bfr[nf] = *(const bf16x8*)(ys + p * 128 + slot * 8);
      }
#pragma unroll
      for (int mf = 0; mf < 4; ++mf)
#pragma unroll
        for (int nf = 0; nf < 4; ++nf)
          acc[mf][nf] = __builtin_amdgcn_mfma_f32_16x16x32_bf16(a[mf], bfr[nf], acc[mf][nf], 0, 0, 0);
    }

    // ---- epilogue: bias + GLU + residual into hsm ----
#pragma unroll
    for (int mf = 0; mf < 2; ++mf)
#pragma unroll
      for (int nf = 0; nf < 4; ++nf)
#pragma unroll
        for (int r = 0; r < 4; ++r) {
          int g = w * 32 + mf * 16 + lk * 4 + r;
          int p = nf * 16 + lr;
          float vv1 = acc[mf][nf][r] + b_out[e * 256 + g];
          float vv2 = acc[mf + 2][nf][r] + b_out[e * 256 + 128 + g];
          float sig = 1.f / (1.f + expf(-vv2));
          int idx = HIDX(g, p);
          hsm[idx] = hsm[idx] + vv1 * sig;
        }
  }
  __syncthreads();

  // ---- store h as bf16, coalesced ushort4 ----
  ushort* hrow = hb + (size_t)bc * 8192;
#pragma unroll
  for (int j = 0; j < 8; ++j) {
    int f = j * 1024 + tid * 4;
    int d = f >> 6, p0 = f & 63;
    float4 hv4 = *(const float4*)(hsm + HIDX(d, p0));
    ushort4 o;
    o.x = f2bf(hv4.x); o.y = f2bf(hv4.y); o.z = f2bf(hv4.z); o.w = f2bf(hv4.w);
    *(ushort4*)(hrow + f) = o;
  }
}

// ---------------- Head: bf16 GEMM (1024 x 96 x 8192), grid (b, kc) = 32x8 ----------------
__global__ __launch_bounds__(256) void head_kernel(const ushort* __restrict__ hb,
                                                   const ushort* __restrict__ wth,
                                                   float* __restrict__ part) {
  __shared__ float sred[12288];   // [4 waves][32 c][96 t]
  int bid = blockIdx.x;
  int b = bid >> 3, kc = bid & 7;
  int tid = threadIdx.x, w = tid >> 6, l = tid & 63;
  int lr = l & 15, lk = l >> 4;
  int kwbase = kc * 1024 + w * 256;
  f32x4 acc[2][6];
#pragma unroll
  for (int m = 0; m < 2; ++m)
#pragma unroll
    for (int n = 0; n < 6; ++n) acc[m][n] = (f32x4){0.f, 0.f, 0.f, 0.f};
#pragma unroll 2
  for (int ks = 0; ks < 8; ++ks) {
    int kb = kwbase + ks * 32 + lk * 8;
    bf16x8 a[2];
#pragma unroll
    for (int mf = 0; mf < 2; ++mf)
      a[mf] = *(const bf16x8*)(hb + (size_t)(b * 32 + mf * 16 + lr) * 8192 + kb);
#pragma unroll
    for (int nf = 0; nf < 6; ++nf) {
      bf16x8 bb = *(const bf16x8*)(wth + (size_t)(nf * 16 + lr) * 8192 + kb);
#pragma unroll
      for (int mf = 0; mf < 2; ++mf)
        acc[mf][nf] = __builtin_amdgcn_mfma_f32_16x16x32_bf16(a[mf], bb, acc[mf][nf], 0, 0, 0);
    }
  }
#pragma unroll
  for (int mf = 0; mf < 2; ++mf)
#pragma unroll
    for (int nf = 0; nf < 6; ++nf)
#pragma unroll
      for (int r = 0; r < 4; ++r) {
        int cc = mf * 16 + lk * 4 + r;
        int t = nf * 16 + lr;
        sred[w * 3072 + cc * 96 + t] = acc[mf][nf][r];
      }
  __syncthreads();
  for (int i = tid; i < 3072; i += 256) {
    float s = sred[i] + sred[3072 + i] + sred[6144 + i] + sred[9216 + i];
    part[(size_t)(kc * 32 + b) * 3072 + i] = s;
  }
}

// ---------------- Reduce partials + bias + denorm ----------------
__global__ __launch_bounds__(256) void reduce_kernel(const float* __restrict__ part,
                                                     const float* __restrict__ b_head,
                                                     const float* __restrict__ meanw,
                                                     const float* __restrict__ stdw,
                                                     float* __restrict__ out) {
  int o = blockIdx.x * 256 + threadIdx.x;
  int c = o & 31;
  int bt = o >> 5;
  int t = bt % 96;
  int b = bt / 96;
  float s = b_head[t];
#pragma unroll
  for (int fs = 0; fs < 8; ++fs)
    s += part[(((size_t)fs * 32 + b) * 32 + c) * 96 + t];
  out[o] = s * stdw[b * 32 + c] + meanw[b * 32 + c];
}

extern "C" void kernel_launch(void* const* d_in, const int* in_sizes, int n_in,
                              void* d_out, int out_size, void* d_ws, size_t ws_size,
                              hipStream_t stream) {
  const float* x_enc   = (const float*)d_in[0];
  const float* W_embed = (const float*)d_in[4];
  const float* ln_g    = (const float*)d_in[5];
  const float* ln_b    = (const float*)d_in[6];
  const float* log_dt  = (const float*)d_in[7];
  const float* arl     = (const float*)d_in[8];
  const float* aimg    = (const float*)d_in[9];
  const float* cre     = (const float*)d_in[10];
  const float* cim     = (const float*)d_in[11];
  const float* dskip   = (const float*)d_in[12];
  const float* wout    = (const float*)d_in[13];
  const float* bout    = (const float*)d_in[14];
  const float* whead   = (const float*)d_in[15];
  const float* bhead   = (const float*)d_in[16];

  float* ws    = (float*)d_ws;
  float* meanw = ws;                        // 1024
  float* stdw  = meanw + 1024;              // 1024
  float* kall  = stdw + 1024;               // 24576
  ushort* wt   = (ushort*)(kall + 24576);   // 98304 ushorts = 49152 floats
  ushort* wth  = (ushort*)(kall + 24576 + 49152);   // 786432 ushorts = 393216 floats
  float* pet   = kall + 24576 + 49152 + 393216;     // 8192
  ushort* hb   = (ushort*)(pet + 8192);     // 8388608 ushorts = 4194304 floats
  float* partw = pet + 8192 + 4194304;      // 786432

  float* out = (float*)d_out;

  prep_kernel<<<99, 256, 0, stream>>>(wout, whead, wt, wth, pet);
  kcomp_kernel<<<384, 64, 0, stream>>>(log_dt, arl, aimg, cre, cim, kall);
  fused_kernel<<<1024, 256, 0, stream>>>(x_enc, W_embed, pet, kall, ln_g, ln_b,
                                         dskip, wt, bout, hb, meanw, stdw);
  head_kernel<<<256, 256, 0, stream>>>(hb, wth, partw);
  reduce_kernel<<<384, 256, 0, stream>>>(partw, bhead, meanw, stdw, out);
}

// Round 5
// 229.549 us; speedup vs baseline: 1.2567x; 1.1051x over previous
//
#include <hip/hip_runtime.h>
#include <math.h>

// B=32, L=512, CIN=32, D=128, N=64, E=3, PL=16, ST=8, PRED=96, P=64, BC=1024
// Fused: RevIN + embed + 3x(LN->conv->GELU->GLU MFMA->residual) with h in LDS.
// R5: anti-spill pass. Plain __launch_bounds__(256) (LDS caps occupancy at 2 blocks/CU
// anyway, so VGPRs up to 256 are free); conv y-chunked (16 live, not 32); sched_barrier(0)
// at phase boundaries to stop cross-phase hoisting that inflated peak liveness.

typedef __attribute__((ext_vector_type(8))) short bf16x8;
typedef __attribute__((ext_vector_type(4))) float f32x4;

__device__ __forceinline__ ushort f2bf(float f) {
  uint u = __float_as_uint(f);
  return (ushort)((u + 0x7FFFu + ((u >> 16) & 1u)) >> 16);
}

// z-tile swizzle (LN write / conv read), 2-way max
#define ZIDX(p, d) ((p) * 128 + ((d) ^ (((p) & 7) << 2)))
// h-tile swizzle: bit4 of p XORed with (d^(d>>2))&1
#define HIDX(d, p) ((d) * 64 + ((p) ^ (((((d) >> 2) ^ (d)) & 1) << 4)))

// ---------------- S4D kernel K[e][p][h] ----------------
__global__ __launch_bounds__(64) void kcomp_kernel(const float* __restrict__ log_dt,
                                                   const float* __restrict__ arl,
                                                   const float* __restrict__ aimg,
                                                   const float* __restrict__ cre,
                                                   const float* __restrict__ cim,
                                                   float* __restrict__ K_all_t) {
  int bid = blockIdx.x;
  int e = bid >> 7, hh = bid & 127;
  int lane = threadIdx.x;
  __shared__ float cr[64], ci[64], dr[64], di[64];
  float dt = expf(log_dt[e * 128 + hh]);
  {
    int n = lane;
    size_t base = ((size_t)e * 128 + hh) * 64 + n;
    float are = -expf(arl[base]);
    float aim = aimg[base];
    float dre = are * dt, dim = aim * dt;
    float ex = expf(dre);
    float cs = cosf(dim), sn = sinf(dim);
    float er = ex * cs - 1.f, ei = ex * sn;
    float invd = 1.f / (are * are + aim * aim);
    float qr = (er * are + ei * aim) * invd;
    float qi = (ei * are - er * aim) * invd;
    float tr = cre[base], ti = cim[base];
    cr[n] = tr * qr - ti * qi;
    ci[n] = tr * qi + ti * qr;
    dr[n] = dre; di[n] = dim;
  }
  __syncthreads();
  int p = lane;
  float fp = (float)p;
  float sum = 0.f;
#pragma unroll 4
  for (int n = 0; n < 64; ++n) {
    float er = expf(dr[n] * fp);
    float ang = di[n] * fp;
    sum += er * (cr[n] * cosf(ang) - ci[n] * sinf(ang));
  }
  K_all_t[(size_t)e * 8192 + p * 128 + hh] = 2.f * sum;
}

// ---------------- Prep: bf16 W_out^T, bf16 W_head^T, PE table [d][p] ----------------
__global__ __launch_bounds__(256) void prep_kernel(const float* __restrict__ W_out,
                                                   const float* __restrict__ W_head,
                                                   ushort* __restrict__ wt,
                                                   ushort* __restrict__ wth,
                                                   float* __restrict__ pet) {
  __shared__ ushort lbuf[12800];
  int bid = blockIdx.x, tid = threadIdx.x;
  if (bid < 64) {                 // W_head^T tile: wth[t][f] (96 x 8192)
    int f0 = bid << 7;
    for (int i = tid; i < 12288; i += 256) {
      int f = i / 96, t = i - f * 96;
      lbuf[f * 100 + t] = f2bf(W_head[(size_t)(f0 + f) * 96 + t]);
    }
    __syncthreads();
    for (int i = tid; i < 12288; i += 256) {
      int t = i >> 7, f = i & 127;
      wth[(size_t)t * 8192 + f0 + f] = lbuf[f * 100 + t];
    }
  } else if (bid < 67) {          // W_out^T per e: wt[e][g][h] (256 x 128)
    int e = bid - 64;
    for (int h0 = 0; h0 < 128; h0 += 32) {
      __syncthreads();
      for (int i = tid; i < 8192; i += 256) {
        int hh = i >> 8, g = i & 255;
        lbuf[hh * 260 + g] = f2bf(W_out[e * 32768 + (h0 + hh) * 256 + g]);
      }
      __syncthreads();
      for (int i = tid; i < 8192; i += 256) {
        int g = i >> 5, hh = i & 31;
        wt[(size_t)(e * 256 + g) * 128 + h0 + hh] = lbuf[hh * 260 + g];
      }
    }
  } else {                        // PE table transposed: pet[d*64+p]
    int i = (bid - 67) * 256 + tid;
    int d = i >> 6, p = i & 63;
    float freq = expf((float)(d & ~1) * (-0.0719557841f));  // -ln(10000)/128
    float ang = (float)p * freq;
    pet[i] = (d & 1) ? cosf(ang) : sinf(ang);
  }
}

// ---------------- Fused: RevIN + embed + 3 layers, h resident in LDS ----------------
__global__ __launch_bounds__(256) void fused_kernel(const float* __restrict__ x,
                                                    const float* __restrict__ W_embed,
                                                    const float* __restrict__ pet,
                                                    const float* __restrict__ K_all_t,
                                                    const float* __restrict__ ln_g,
                                                    const float* __restrict__ ln_b,
                                                    const float* __restrict__ D_skip,
                                                    const ushort* __restrict__ wt,
                                                    const float* __restrict__ b_out,
                                                    ushort* __restrict__ hb,
                                                    float* __restrict__ meanw,
                                                    float* __restrict__ stdw) {
  __shared__ float hsm[8192];     // h residual stream, HIDX-swizzled [128 d][64 p]  (32 KB)
  __shared__ float zl[8192];      // z (ZIDX-swizzled); xts/Wel during embed         (32 KB)
  __shared__ ushort ys[8192];     // y^T bf16 [64 p][128 h], 16B-slot XOR swizzle    (16 KB)
  int bc = blockIdx.x, tid = threadIdx.x;
  int b = bc >> 5, c = bc & 31;
  int w = tid >> 6, l = tid & 63;

  // ---- RevIN: mean/std over L=512 for this (b,c) ----
  const float* xb = x + (size_t)b * 512 * 32 + c;
  float v0 = xb[(size_t)tid * 32];
  float v1 = xb[(size_t)(tid + 256) * 32];
  float s = v0 + v1, sq = v0 * v0 + v1 * v1;
#pragma unroll
  for (int off = 1; off < 64; off <<= 1) {
    s += __shfl_xor(s, off);
    sq += __shfl_xor(sq, off);
  }
  if (l == 0) { hsm[w] = s; hsm[4 + w] = sq; }
  __syncthreads();
  s = hsm[0] + hsm[1] + hsm[2] + hsm[3];
  sq = hsm[4] + hsm[5] + hsm[6] + hsm[7];
  float mu = s * (1.f / 512.f);
  float var = sq * (1.f / 512.f) - mu * mu;
  float sd = sqrtf(var + 1e-5f);
  float inv = 1.f / sd;
  if (tid == 0) { meanw[bc] = mu; stdw[bc] = sd; }
  float* xts = zl;          // [528]
  float* Wel = zl + 1024;   // [2048]
  xts[tid] = (v0 - mu) * inv;
  xts[tid + 256] = (v1 - mu) * inv;
  if (tid == 255) {
    float ev = (v1 - mu) * inv;
#pragma unroll
    for (int i = 0; i < 16; ++i) xts[512 + i] = ev;
  }
  for (int i = tid; i < 2048; i += 256) Wel[i] = W_embed[i];
  __syncthreads();

  // ---- Patch embed into hsm ----
  {
    int p = tid & 63, dg = tid >> 6;
    float xr[16];
    const float4* xf = (const float4*)xts;
#pragma unroll
    for (int i = 0; i < 4; ++i) {
      float4 a = xf[p * 2 + i];
      xr[4 * i] = a.x; xr[4 * i + 1] = a.y; xr[4 * i + 2] = a.z; xr[4 * i + 3] = a.w;
    }
#pragma unroll 4
    for (int dd = 0; dd < 32; ++dd) {
      int d = dg * 32 + dd;
      float acc = 0.f;
#pragma unroll
      for (int k = 0; k < 16; ++k) acc += xr[k] * Wel[k * 128 + d];
      hsm[HIDX(d, p)] = acc + pet[d * 64 + p];
    }
  }

  int hh = tid & 127, pg = tid >> 7;
  int lr = l & 15, lk = l >> 4;

#pragma unroll 1
  for (int e = 0; e < 3; ++e) {
    __syncthreads();   // barrier A: prev epilogue hsm writes visible; zl free
    // ---- LayerNorm over D at each p (4 threads per p) ----
    {
      int p = tid >> 2, sub = tid & 3;
      float hv[32];
      float ls = 0.f, lq = 0.f;
#pragma unroll
      for (int j = 0; j < 32; ++j) {
        int d = sub + 4 * j;
        float vv = hsm[HIDX(d, p)];
        hv[j] = vv; ls += vv; lq += vv * vv;
      }
      ls += __shfl_xor(ls, 1); ls += __shfl_xor(ls, 2);
      lq += __shfl_xor(lq, 1); lq += __shfl_xor(lq, 2);
      float lmu = ls * (1.f / 128.f);
      float lvar = lq * (1.f / 128.f) - lmu * lmu;
      float istd = rsqrtf(lvar + 1e-5f);
#pragma unroll
      for (int j = 0; j < 32; ++j) {
        int d = sub + 4 * j;
        zl[ZIDX(p, d)] = (hv[j] - lmu) * istd * ln_g[e * 128 + d] + ln_b[e * 128 + d];
      }
    }
    __builtin_amdgcn_sched_barrier(0);   // keep kr loads out of the LN live range
    // K into registers (L2-resident, coalesced per wave)
    float kr[64];
    {
      const float* kb = K_all_t + e * 8192 + hh;
#pragma unroll
      for (int i = 0; i < 64; ++i) kr[i] = kb[i * 128];
    }
    float dsk = D_skip[e * 128 + hh];
    __syncthreads();   // barrier B: zl complete
    __builtin_amdgcn_sched_barrier(0);

    // ---- causal conv, interleaved p-split, j-chunked (16 accumulators live) ----
    // chunk 0: j in [0,16) -> p = 2j+pg in [pg, 30+pg]
    {
      float y[16];
#pragma unroll
      for (int j = 0; j < 16; ++j) y[j] = 0.f;
      if (pg == 0) {
#pragma unroll
        for (int q = 0; q < 31; ++q) {
          float zv = zl[ZIDX(q, hh)];
#pragma unroll
          for (int j = (q + 1) >> 1; j < 16; ++j) y[j] += zv * kr[2 * j - q];
        }
      } else {
#pragma unroll
        for (int q = 0; q < 32; ++q) {
          float zv = zl[ZIDX(q, hh)];
#pragma unroll
          for (int j = q >> 1; j < 16; ++j) y[j] += zv * kr[2 * j + 1 - q];
        }
      }
      int slot = hh >> 3;
#pragma unroll
      for (int j = 0; j < 16; ++j) {
        int p = 2 * j + pg;
        float u = zl[ZIDX(p, hh)];
        float t = y[j] + u * dsk;
        float g = 0.5f * t * (1.f + erff(t * 0.70710678f));
        ys[p * 128 + ((slot ^ (p & 15)) << 3) + (hh & 7)] = f2bf(g);
      }
    }
    __builtin_amdgcn_sched_barrier(0);   // don't interleave chunk 0 and chunk 1
    // chunk 1: j in [16,32) -> p = 2j+pg in [32+pg, 62+pg]
    {
      float y[16];
#pragma unroll
      for (int j = 0; j < 16; ++j) y[j] = 0.f;
      if (pg == 0) {
#pragma unroll
        for (int q = 0; q < 63; ++q) {
          float zv = zl[ZIDX(q, hh)];
          int jlo = (q + 1) >> 1; if (jlo < 16) jlo = 16;
#pragma unroll
          for (int j = 16; j < 32; ++j)
            if (j >= jlo) y[j - 16] += zv * kr[2 * j - q];
        }
      } else {
#pragma unroll
        for (int q = 0; q < 64; ++q) {
          float zv = zl[ZIDX(q, hh)];
          int jlo = q >> 1; if (jlo < 16) jlo = 16;
#pragma unroll
          for (int j = 16; j < 32; ++j)
            if (j >= jlo) y[j - 16] += zv * kr[2 * j + 1 - q];
        }
      }
      int slot = hh >> 3;
#pragma unroll
      for (int j = 16; j < 32; ++j) {
        int p = 2 * j + pg;
        float u = zl[ZIDX(p, hh)];
        float t = y[j - 16] + u * dsk;
        float g = 0.5f * t * (1.f + erff(t * 0.70710678f));
        ys[p * 128 + ((slot ^ (p & 15)) << 3) + (hh & 7)] = f2bf(g);
      }
    }
    __syncthreads();   // barrier C: ys complete
    __builtin_amdgcn_sched_barrier(0);

    // ---- MFMA GLU linear: v[g][p] = sum_h Wt[g][h] * y^T[p][h] ----
    f32x4 acc[4][4];
#pragma unroll
    for (int m = 0; m < 4; ++m)
#pragma unroll
      for (int n = 0; n < 4; ++n) acc[m][n] = (f32x4){0.f, 0.f, 0.f, 0.f};
    const ushort* wbase = wt + (size_t)e * 32768;
#pragma unroll
    for (int ks = 0; ks < 4; ++ks) {
      int kofs = ks * 32 + lk * 8;
      bf16x8 a[4], bfr[4];
#pragma unroll
      for (int mf = 0; mf < 4; ++mf) {
        int gm = (mf < 2) ? (w * 32 + mf * 16) : (128 + w * 32 + (mf - 2) * 16);
        a[mf] = *(const bf16x8*)(wbase + (size_t)(gm + lr) * 128 + kofs);
      }
#pragma unroll
      for (int nf = 0; nf < 4; ++nf) {
        int p = nf * 16 + lr;
        int slot = (ks * 4 + lk) ^ (p & 15);
        bfr[nf] = *(const bf16x8*)(ys + p * 128 + slot * 8);
      }
#pragma unroll
      for (int mf = 0; mf < 4; ++mf)
#pragma unroll
        for (int nf = 0; nf < 4; ++nf)
          acc[mf][nf] = __builtin_amdgcn_mfma_f32_16x16x32_bf16(a[mf], bfr[nf], acc[mf][nf], 0, 0, 0);
    }

    // ---- epilogue: bias + GLU + residual into hsm ----
#pragma unroll
    for (int mf = 0; mf < 2; ++mf)
#pragma unroll
      for (int nf = 0; nf < 4; ++nf)
#pragma unroll
        for (int r = 0; r < 4; ++r) {
          int g = w * 32 + mf * 16 + lk * 4 + r;
          int p = nf * 16 + lr;
          float vv1 = acc[mf][nf][r] + b_out[e * 256 + g];
          float vv2 = acc[mf + 2][nf][r] + b_out[e * 256 + 128 + g];
          float sig = 1.f / (1.f + expf(-vv2));
          int idx = HIDX(g, p);
          hsm[idx] = hsm[idx] + vv1 * sig;
        }
  }
  __syncthreads();

  // ---- store h as bf16, coalesced ushort4 ----
  ushort* hrow = hb + (size_t)bc * 8192;
#pragma unroll
  for (int j = 0; j < 8; ++j) {
    int f = j * 1024 + tid * 4;
    int d = f >> 6, p0 = f & 63;
    float4 hv4 = *(const float4*)(hsm + HIDX(d, p0));
    ushort4 o;
    o.x = f2bf(hv4.x); o.y = f2bf(hv4.y); o.z = f2bf(hv4.z); o.w = f2bf(hv4.w);
    *(ushort4*)(hrow + f) = o;
  }
}

// ---------------- Head: bf16 GEMM (1024 x 96 x 8192), grid (b, kc) = 32x8 ----------------
__global__ __launch_bounds__(256) void head_kernel(const ushort* __restrict__ hb,
                                                   const ushort* __restrict__ wth,
                                                   float* __restrict__ part) {
  __shared__ float sred[12288];   // [4 waves][32 c][96 t]
  int bid = blockIdx.x;
  int b = bid >> 3, kc = bid & 7;
  int tid = threadIdx.x, w = tid >> 6, l = tid & 63;
  int lr = l & 15, lk = l >> 4;
  int kwbase = kc * 1024 + w * 256;
  f32x4 acc[2][6];
#pragma unroll
  for (int m = 0; m < 2; ++m)
#pragma unroll
    for (int n = 0; n < 6; ++n) acc[m][n] = (f32x4){0.f, 0.f, 0.f, 0.f};
#pragma unroll 2
  for (int ks = 0; ks < 8; ++ks) {
    int kb = kwbase + ks * 32 + lk * 8;
    bf16x8 a[2];
#pragma unroll
    for (int mf = 0; mf < 2; ++mf)
      a[mf] = *(const bf16x8*)(hb + (size_t)(b * 32 + mf * 16 + lr) * 8192 + kb);
#pragma unroll
    for (int nf = 0; nf < 6; ++nf) {
      bf16x8 bb = *(const bf16x8*)(wth + (size_t)(nf * 16 + lr) * 8192 + kb);
#pragma unroll
      for (int mf = 0; mf < 2; ++mf)
        acc[mf][nf] = __builtin_amdgcn_mfma_f32_16x16x32_bf16(a[mf], bb, acc[mf][nf], 0, 0, 0);
    }
  }
#pragma unroll
  for (int mf = 0; mf < 2; ++mf)
#pragma unroll
    for (int nf = 0; nf < 6; ++nf)
#pragma unroll
      for (int r = 0; r < 4; ++r) {
        int cc = mf * 16 + lk * 4 + r;
        int t = nf * 16 + lr;
        sred[w * 3072 + cc * 96 + t] = acc[mf][nf][r];
      }
  __syncthreads();
  for (int i = tid; i < 3072; i += 256) {
    float s = sred[i] + sred[3072 + i] + sred[6144 + i] + sred[9216 + i];
    part[(size_t)(kc * 32 + b) * 3072 + i] = s;
  }
}

// ---------------- Reduce partials + bias + denorm ----------------
__global__ __launch_bounds__(256) void reduce_kernel(const float* __restrict__ part,
                                                     const float* __restrict__ b_head,
                                                     const float* __restrict__ meanw,
                                                     const float* __restrict__ stdw,
                                                     float* __restrict__ out) {
  int o = blockIdx.x * 256 + threadIdx.x;
  int c = o & 31;
  int bt = o >> 5;
  int t = bt % 96;
  int b = bt / 96;
  float s = b_head[t];
#pragma unroll
  for (int fs = 0; fs < 8; ++fs)
    s += part[(((size_t)fs * 32 + b) * 32 + c) * 96 + t];
  out[o] = s * stdw[b * 32 + c] + meanw[b * 32 + c];
}

extern "C" void kernel_launch(void* const* d_in, const int* in_sizes, int n_in,
                              void* d_out, int out_size, void* d_ws, size_t ws_size,
                              hipStream_t stream) {
  const float* x_enc   = (const float*)d_in[0];
  const float* W_embed = (const float*)d_in[4];
  const float* ln_g    = (const float*)d_in[5];
  const float* ln_b    = (const float*)d_in[6];
  const float* log_dt  = (const float*)d_in[7];
  const float* arl     = (const float*)d_in[8];
  const float* aimg    = (const float*)d_in[9];
  const float* cre     = (const float*)d_in[10];
  const float* cim     = (const float*)d_in[11];
  const float* dskip   = (const float*)d_in[12];
  const float* wout    = (const float*)d_in[13];
  const float* bout    = (const float*)d_in[14];
  const float* whead   = (const float*)d_in[15];
  const float* bhead   = (const float*)d_in[16];

  float* ws    = (float*)d_ws;
  float* meanw = ws;                        // 1024
  float* stdw  = meanw + 1024;              // 1024
  float* kall  = stdw + 1024;               // 24576
  ushort* wt   = (ushort*)(kall + 24576);   // 98304 ushorts = 49152 floats
  ushort* wth  = (ushort*)(kall + 24576 + 49152);   // 786432 ushorts = 393216 floats
  float* pet   = kall + 24576 + 49152 + 393216;     // 8192
  ushort* hb   = (ushort*)(pet + 8192);     // 8388608 ushorts = 4194304 floats
  float* partw = pet + 8192 + 4194304;      // 786432

  float* out = (float*)d_out;

  prep_kernel<<<99, 256, 0, stream>>>(wout, whead, wt, wth, pet);
  kcomp_kernel<<<384, 64, 0, stream>>>(log_dt, arl, aimg, cre, cim, kall);
  fused_kernel<<<1024, 256, 0, stream>>>(x_enc, W_embed, pet, kall, ln_g, ln_b,
                                         dskip, wt, bout, hb, meanw, stdw);
  head_kernel<<<256, 256, 0, stream>>>(hb, wth, partw);
  reduce_kernel<<<384, 256, 0, stream>>>(partw, bhead, meanw, stdw, out);
}